// Round 4
// baseline (1886.128 us; speedup 1.0000x reference)
//
#include <hip/hip_runtime.h>
#include <hip/hip_fp16.h>

#define N_NODES 100000
#define N_EDGES 1600000
#define C_DIM 128
#define EC_DIM 16
#define L_LAYERS 3
#define G_GRAPHS 256
#define GN_EPS 1e-5f
#define SCAN_BLOCKS 391   // ceil(100000/256)

__device__ __forceinline__ float silu_f(float v) {
    return v / (1.0f + __expf(-v));
}

__device__ __forceinline__ float4 ld4(const float* p) { return *(const float4*)p; }
__device__ __forceinline__ void st4(float* p, float4 v) { *(float4*)p = v; }
__device__ __forceinline__ float4 fma4(float s, float4 w, float4 a) {
    a.x = fmaf(s, w.x, a.x); a.y = fmaf(s, w.y, a.y);
    a.z = fmaf(s, w.z, a.z); a.w = fmaf(s, w.w, a.w);
    return a;
}

// ---------------- graph bookkeeping (GraphNorm segments) ----------------

__global__ void zero_cnt_kernel(int* cnt) { cnt[threadIdx.x] = 0; }

__global__ void count_kernel(const int* __restrict__ batch, int* __restrict__ cnt) {
    int i = blockIdx.x * blockDim.x + threadIdx.x;
    if (i < N_NODES) atomicAdd(&cnt[batch[i]], 1);
}

__global__ void scan_kernel(const int* __restrict__ cnt, int* __restrict__ start,
                            float* __restrict__ cntf) {
    __shared__ int s[G_GRAPHS];
    int t = threadIdx.x;
    int v = cnt[t];
    s[t] = v;
    __syncthreads();
    for (int off = 1; off < G_GRAPHS; off <<= 1) {
        int add = (t >= off) ? s[t - off] : 0;
        __syncthreads();
        s[t] += add;
        __syncthreads();
    }
    start[t] = s[t] - v;
    cntf[t] = (float)v;
}

// ---------------- CSR build (by dst) ----------------

__global__ void deg_count_kernel(const int* __restrict__ eidx, int* __restrict__ deg) {
    int e = blockIdx.x * blockDim.x + threadIdx.x;
    if (e < N_EDGES) atomicAdd(&deg[eidx[N_EDGES + e]], 1);
}

__global__ void scanA_kernel(const int* __restrict__ deg, int* __restrict__ rpl,
                             int* __restrict__ bsum) {
    __shared__ int s[256];
    int i = blockIdx.x * 256 + threadIdx.x;
    int v = (i < N_NODES) ? deg[i] : 0;
    s[threadIdx.x] = v;
    __syncthreads();
    for (int off = 1; off < 256; off <<= 1) {
        int add = (threadIdx.x >= off) ? s[threadIdx.x - off] : 0;
        __syncthreads();
        s[threadIdx.x] += add;
        __syncthreads();
    }
    if (i < N_NODES) rpl[i] = s[threadIdx.x] - v;
    if (threadIdx.x == 255) bsum[blockIdx.x] = s[255];
}

__global__ void scanB_kernel(const int* __restrict__ bsum, int* __restrict__ boff) {
    __shared__ int s[512];
    int t = threadIdx.x;
    int v = (t < SCAN_BLOCKS) ? bsum[t] : 0;
    s[t] = v;
    __syncthreads();
    for (int off = 1; off < 512; off <<= 1) {
        int add = (t >= off) ? s[t - off] : 0;
        __syncthreads();
        s[t] += add;
        __syncthreads();
    }
    if (t < SCAN_BLOCKS) boff[t] = s[t] - v;
}

__global__ void scanC_kernel(const int* __restrict__ rpl, const int* __restrict__ boff,
                             int* __restrict__ rp, int* __restrict__ cursor) {
    int i = blockIdx.x * 256 + threadIdx.x;
    if (i < N_NODES) {
        int v = rpl[i] + boff[blockIdx.x];
        rp[i] = v;
        cursor[i] = v;
    }
    if (i == 0) rp[N_NODES] = N_EDGES;
}

__global__ void fill_kernel(const int* __restrict__ eidx, int* __restrict__ cursor,
                            int* __restrict__ srcs, int* __restrict__ eid) {
    int e = blockIdx.x * blockDim.x + threadIdx.x;
    if (e >= N_EDGES) return;
    int src = eidx[e];
    int dst = eidx[N_EDGES + e];
    int pos = atomicAdd(&cursor[dst], 1);
    srcs[pos] = src;
    eid[pos] = e;
}

// ---------------- one-time reorder: eac[pos] = edge_attr[eid[pos]] --------
__global__ __launch_bounds__(256) void eacopy_kernel(
    const float* __restrict__ ea, const int* __restrict__ eid,
    float4* __restrict__ eac)
{
    long long t = (long long)blockIdx.x * blockDim.x + threadIdx.x;
    int pos = (int)(t >> 2), q = (int)(t & 3);
    if (pos >= N_EDGES) return;
    int e = eid[pos];
    eac[(size_t)pos * 4 + q] = ((const float4*)(ea + (size_t)e * EC_DIM))[q];
}

// ---------------- one-time cast: xh = fp16(x) ----------------
__global__ __launch_bounds__(256) void xcast_kernel(
    const float* __restrict__ x, __half2* __restrict__ xh)
{
    int i = blockIdx.x * blockDim.x + threadIdx.x;   // N*C/2 elements
    if (i < N_NODES * C_DIM / 2) {
        float2 v = ((const float2*)x)[i];
        xh[i] = __floats2half2_rn(v.x, v.y);
    }
}

// ---------------- fused gather ----------------
// One wave per node; the wave walks the node's CSR range one edge per
// iteration. n is readfirstlane'd so j / srcs[j] / the ea row address are
// provably wave-uniform -> ea lands in SGPRs via s_load. W (16 float2 =
// 32 VGPRs) is loaded once and pinned in VGPRs with an empty asm
// ("+v") so the compiler CANNOT rematerialize the loads inside the loop
// (round-3 evidence: VGPR_Count=28 -> W was reloaded every edge, 3.5x
// instruction bloat). Lane owns 2 channels.

#define DECLW(k) float2 w##k = *(const float2*)(Wp + (k) * C_DIM);
#define KEEPW(k) asm volatile("" : "+v"(w##k.x), "+v"(w##k.y));

#define EDGE_PROJ(QA, QB, QC, QD, ZX, ZY) \
    ZX = b2.x; ZY = b2.y; \
    ZX = fmaf(QA.x, w0.x,  ZX); ZY = fmaf(QA.x, w0.y,  ZY); \
    ZX = fmaf(QA.y, w1.x,  ZX); ZY = fmaf(QA.y, w1.y,  ZY); \
    ZX = fmaf(QA.z, w2.x,  ZX); ZY = fmaf(QA.z, w2.y,  ZY); \
    ZX = fmaf(QA.w, w3.x,  ZX); ZY = fmaf(QA.w, w3.y,  ZY); \
    ZX = fmaf(QB.x, w4.x,  ZX); ZY = fmaf(QB.x, w4.y,  ZY); \
    ZX = fmaf(QB.y, w5.x,  ZX); ZY = fmaf(QB.y, w5.y,  ZY); \
    ZX = fmaf(QB.z, w6.x,  ZX); ZY = fmaf(QB.z, w6.y,  ZY); \
    ZX = fmaf(QB.w, w7.x,  ZX); ZY = fmaf(QB.w, w7.y,  ZY); \
    ZX = fmaf(QC.x, w8.x,  ZX); ZY = fmaf(QC.x, w8.y,  ZY); \
    ZX = fmaf(QC.y, w9.x,  ZX); ZY = fmaf(QC.y, w9.y,  ZY); \
    ZX = fmaf(QC.z, w10.x, ZX); ZY = fmaf(QC.z, w10.y, ZY); \
    ZX = fmaf(QC.w, w11.x, ZX); ZY = fmaf(QC.w, w11.y, ZY); \
    ZX = fmaf(QD.x, w12.x, ZX); ZY = fmaf(QD.x, w12.y, ZY); \
    ZX = fmaf(QD.y, w13.x, ZX); ZY = fmaf(QD.y, w13.y, ZY); \
    ZX = fmaf(QD.z, w14.x, ZX); ZY = fmaf(QD.z, w14.y, ZY); \
    ZX = fmaf(QD.w, w15.x, ZX); ZY = fmaf(QD.w, w15.y, ZY);

template<bool BIG>
__global__ __launch_bounds__(256) void gatherf_kernel(
    const float* __restrict__ x, const __half* __restrict__ xh,
    const float* __restrict__ ea, const float* __restrict__ eac,
    const int* __restrict__ srcs, const int* __restrict__ eid,
    const int* __restrict__ rp,
    const float* __restrict__ W, const float* __restrict__ bias,
    float* __restrict__ hb)
{
    int n = (blockIdx.x * blockDim.x + threadIdx.x) >> 6;
    n = __builtin_amdgcn_readfirstlane(n);   // provably wave-uniform
    if (n >= N_NODES) return;
    const int lane = threadIdx.x & 63;
    const int c2 = lane * 2;
    const float* Wp = W + c2;
    DECLW(0)  DECLW(1)  DECLW(2)  DECLW(3)
    DECLW(4)  DECLW(5)  DECLW(6)  DECLW(7)
    DECLW(8)  DECLW(9)  DECLW(10) DECLW(11)
    DECLW(12) DECLW(13) DECLW(14) DECLW(15)
    // pin W in VGPRs: opaque to LICM/remat
    KEEPW(0)  KEEPW(1)  KEEPW(2)  KEEPW(3)
    KEEPW(4)  KEEPW(5)  KEEPW(6)  KEEPW(7)
    KEEPW(8)  KEEPW(9)  KEEPW(10) KEEPW(11)
    KEEPW(12) KEEPW(13) KEEPW(14) KEEPW(15)
    const float2 b2 = *(const float2*)(bias + c2);

    float accx = 0.f, accy = 0.f;
    const int beg = rp[n], end = rp[n + 1];
    for (int j = beg; j < end; ++j) {
        const int src = srcs[j];            // uniform -> s_load
        float4 A0, A1, A2, A3;
        float xsx, xsy;
        if (BIG) {
            const float* ep = eac + (size_t)j * EC_DIM;   // uniform row
            A0 = ld4(ep);     A1 = ld4(ep + 4);
            A2 = ld4(ep + 8); A3 = ld4(ep + 12);
            const __half2 xv = *(const __half2*)(xh + (size_t)src * C_DIM + c2);
            const float2 xf = __half22float2(xv);
            xsx = xf.x; xsy = xf.y;
        } else {
            const int e = eid[j];                          // uniform
            const float* ep = ea + (size_t)e * EC_DIM;     // uniform row
            A0 = ld4(ep);     A1 = ld4(ep + 4);
            A2 = ld4(ep + 8); A3 = ld4(ep + 12);
            const float2 xf = *(const float2*)(x + (size_t)src * C_DIM + c2);
            xsx = xf.x; xsy = xf.y;
        }
        float zx, zy;
        EDGE_PROJ(A0, A1, A2, A3, zx, zy)
        accx += fmaxf(xsx + silu_f(zx), 0.f);
        accy += fmaxf(xsy + silu_f(zy), 0.f);
    }
    const float2 xo = *(const float2*)(x + (size_t)n * C_DIM + c2);
    *(float2*)(hb + (size_t)n * C_DIM + c2) = make_float2(xo.x + accx, xo.y + accy);
}

// ---------------- fp32 GEMM: out[N,128] = act(A[N,128] @ W[128,128] + b) ----
template<bool SILU>
__global__ __launch_bounds__(256) void gemm128_kernel(
    const float* __restrict__ A, const float* __restrict__ W,
    const float* __restrict__ bias, float* __restrict__ out)
{
    __shared__ float Wl[C_DIM * C_DIM];   // 64 KB
    const int tid = threadIdx.x;
    const int rowbase = blockIdx.x * 32;
#pragma unroll
    for (int i = 0; i < 16; ++i)
        ((float4*)Wl)[i * 256 + tid] = ((const float4*)W)[i * 256 + tid];
    __syncthreads();

    const int cx = tid & 31;
    const int ry = tid >> 5;
    const float4 bias4 = ld4(bias + cx * 4);
    float4 acc[4] = {bias4, bias4, bias4, bias4};
    const float* Ab = A + (size_t)(rowbase + ry * 4) * C_DIM;

    for (int k = 0; k < C_DIM; k += 4) {
        float4 a[4], w[4];
#pragma unroll
        for (int rr = 0; rr < 4; ++rr) a[rr] = ld4(Ab + rr * C_DIM + k);
#pragma unroll
        for (int kk = 0; kk < 4; ++kk) w[kk] = *(const float4*)&Wl[(k + kk) * C_DIM + cx * 4];
#pragma unroll
        for (int rr = 0; rr < 4; ++rr) {
            acc[rr] = fma4(a[rr].x, w[0], acc[rr]);
            acc[rr] = fma4(a[rr].y, w[1], acc[rr]);
            acc[rr] = fma4(a[rr].z, w[2], acc[rr]);
            acc[rr] = fma4(a[rr].w, w[3], acc[rr]);
        }
    }
#pragma unroll
    for (int rr = 0; rr < 4; ++rr) {
        float4 v = acc[rr];
        if (SILU) { v.x = silu_f(v.x); v.y = silu_f(v.y); v.z = silu_f(v.z); v.w = silu_f(v.w); }
        st4(out + (size_t)(rowbase + ry * 4 + rr) * C_DIM + cx * 4, v);
    }
}

// ---------------- GraphNorm ----------------
__global__ __launch_bounds__(1024) void gn_reduce_kernel(
    const float* __restrict__ h, const int* __restrict__ start,
    const int* __restrict__ cnt, const float* __restrict__ cntf,
    const float* __restrict__ ms, float* __restrict__ meansc,
    float* __restrict__ rstd)
{
    const int g = blockIdx.x;
    const int c = threadIdx.x & 127;
    const int sub = threadIdx.x >> 7;       // 0..7
    const int s0 = start[g];
    const int n = cnt[g];
    float sum = 0.f, sq = 0.f;
    for (int r = sub; r < n; r += 8) {
        float v = h[(size_t)(s0 + r) * C_DIM + c];
        sum += v; sq += v * v;
    }
    __shared__ float ls[1024], lq[1024];
    ls[threadIdx.x] = sum; lq[threadIdx.x] = sq;
    __syncthreads();
    if (threadIdx.x < 512) {
        ls[threadIdx.x] += ls[threadIdx.x + 512];
        lq[threadIdx.x] += lq[threadIdx.x + 512];
    }
    __syncthreads();
    if (threadIdx.x < 256) {
        ls[threadIdx.x] += ls[threadIdx.x + 256];
        lq[threadIdx.x] += lq[threadIdx.x + 256];
    }
    __syncthreads();
    if (threadIdx.x < 128) {
        sum = ls[threadIdx.x] + ls[threadIdx.x + 128];
        sq  = lq[threadIdx.x] + lq[threadIdx.x + 128];
        const float cn = cntf[g];
        const float mean = sum / cn;
        const float msq = sq / cn;
        const float s = ms[c];
        const float var = msq - (2.0f * s - s * s) * mean * mean;
        meansc[(size_t)g * C_DIM + c] = mean * s;
        rstd[(size_t)g * C_DIM + c] = 1.0f / sqrtf(var + GN_EPS);
    }
}

__global__ __launch_bounds__(256) void gn_norm_kernel(
    const float* __restrict__ h, const int* __restrict__ batch,
    const float* __restrict__ meansc, const float* __restrict__ rstd,
    const float* __restrict__ gw, const float* __restrict__ gb,
    float* __restrict__ out, __half* __restrict__ xh, int wxh)
{
    const int id = blockIdx.x * blockDim.x + threadIdx.x;
    const int row = id >> 5;
    const int c4 = (id & 31) * 4;
    if (row >= N_NODES) return;
    const int g = batch[row];
    const float4 hv = ld4(h + (size_t)row * C_DIM + c4);
    const float4 m = ld4(meansc + (size_t)g * C_DIM + c4);
    const float4 r = ld4(rstd + (size_t)g * C_DIM + c4);
    const float4 w = ld4(gw + c4);
    const float4 b = ld4(gb + c4);
    float4 o;
    o.x = fmaf((hv.x - m.x) * r.x, w.x, b.x);
    o.y = fmaf((hv.y - m.y) * r.y, w.y, b.y);
    o.z = fmaf((hv.z - m.z) * r.z, w.z, b.z);
    o.w = fmaf((hv.w - m.w) * r.w, w.w, b.w);
    st4(out + (size_t)row * C_DIM + c4, o);
    if (wxh) {
        __half2* xp = (__half2*)(xh + (size_t)row * C_DIM + c4);
        xp[0] = __floats2half2_rn(o.x, o.y);
        xp[1] = __floats2half2_rn(o.z, o.w);
    }
}

// ---------------- launch ----------------

extern "C" void kernel_launch(void* const* d_in, const int* in_sizes, int n_in,
                              void* d_out, int out_size, void* d_ws, size_t ws_size,
                              hipStream_t stream)
{
    const float* x_in      = (const float*)d_in[0];
    const float* edge_attr = (const float*)d_in[1];
    const int*   edge_idx  = (const int*)d_in[2];
    const int*   batch     = (const int*)d_in[3];
    const float* lew       = (const float*)d_in[4];
    const float* leb       = (const float*)d_in[5];
    const float* w1        = (const float*)d_in[6];
    const float* b1        = (const float*)d_in[7];
    const float* w2        = (const float*)d_in[8];
    const float* b2        = (const float*)d_in[9];
    const float* gnw       = (const float*)d_in[10];
    const float* gnb       = (const float*)d_in[11];
    const float* gms       = (const float*)d_in[12];
    float* out = (float*)d_out;

    // workspace layout
    float* hbuf   = (float*)d_ws;                        // N*C
    float* meansc = hbuf + (size_t)N_NODES * C_DIM;      // G*C
    float* rstd   = meansc + (size_t)G_GRAPHS * C_DIM;   // G*C
    float* cntf   = rstd + (size_t)G_GRAPHS * C_DIM;     // G
    int*   cnti   = (int*)(cntf + G_GRAPHS);             // G
    int*   startg = cnti + G_GRAPHS;                     // G
    int*   deg    = startg + G_GRAPHS;                   // N
    int*   rpl    = deg + N_NODES;                       // N
    int*   bsum   = rpl + N_NODES;                       // 512
    int*   boff   = bsum + 512;                          // 512
    int*   rp     = boff + 512;                          // N+1
    int*   cursor = rp + N_NODES + 2;                    // N
    int*   srcs   = cursor + N_NODES;                    // E
    int*   eid    = srcs + N_EDGES;                      // E
    float* eac    = (float*)(eid + N_EDGES);             // E*16 (big only)
    __half* xh    = (__half*)(eac + (size_t)N_EDGES * EC_DIM);  // N*C fp16 (big only)

    const size_t need_big = (size_t)((char*)(xh + (size_t)N_NODES * C_DIM) - (char*)d_ws);
    const bool big = ws_size >= need_big;

    // GraphNorm segment bookkeeping
    zero_cnt_kernel<<<1, G_GRAPHS, 0, stream>>>(cnti);
    count_kernel<<<(N_NODES + 255) / 256, 256, 0, stream>>>(batch, cnti);
    scan_kernel<<<1, G_GRAPHS, 0, stream>>>(cnti, startg, cntf);

    // CSR build (by dst), once per call
    hipMemsetAsync(deg, 0, (size_t)N_NODES * sizeof(int), stream);
    deg_count_kernel<<<(N_EDGES + 255) / 256, 256, 0, stream>>>(edge_idx, deg);
    scanA_kernel<<<SCAN_BLOCKS, 256, 0, stream>>>(deg, rpl, bsum);
    scanB_kernel<<<1, 512, 0, stream>>>(bsum, boff);
    scanC_kernel<<<SCAN_BLOCKS, 256, 0, stream>>>(rpl, boff, rp, cursor);
    fill_kernel<<<(N_EDGES + 255) / 256, 256, 0, stream>>>(edge_idx, cursor, srcs, eid);

    if (big) {
        eacopy_kernel<<<(int)(((size_t)N_EDGES * 4 + 255) / 256), 256, 0, stream>>>(
            edge_attr, eid, (float4*)eac);
        xcast_kernel<<<(int)(((size_t)N_NODES * C_DIM / 2 + 255) / 256), 256, 0, stream>>>(
            x_in, (__half2*)xh);
    }

    const float* cur = x_in;
    for (int l = 0; l < L_LAYERS; ++l) {
        if (big) {
            gatherf_kernel<true><<<(int)(((size_t)N_NODES * 64 + 255) / 256), 256, 0, stream>>>(
                cur, xh, edge_attr, eac, srcs, eid, rp, lew, leb, hbuf);
        } else {
            gatherf_kernel<false><<<(int)(((size_t)N_NODES * 64 + 255) / 256), 256, 0, stream>>>(
                cur, xh, edge_attr, eac, srcs, eid, rp, lew, leb, hbuf);
        }
        gemm128_kernel<true><<<N_NODES / 32, 256, 0, stream>>>(
            hbuf, w1 + (size_t)l * C_DIM * C_DIM, b1 + (size_t)l * C_DIM, out);
        gemm128_kernel<false><<<N_NODES / 32, 256, 0, stream>>>(
            out, w2 + (size_t)l * C_DIM * C_DIM, b2 + (size_t)l * C_DIM, hbuf);
        gn_reduce_kernel<<<G_GRAPHS, 1024, 0, stream>>>(
            hbuf, startg, cnti, cntf, gms + (size_t)l * C_DIM, meansc, rstd);
        gn_norm_kernel<<<(int)(((size_t)N_NODES * 32 + 255) / 256), 256, 0, stream>>>(
            hbuf, batch, meansc, rstd, gnw + (size_t)l * C_DIM, gnb + (size_t)l * C_DIM,
            out, xh, (big && l < L_LAYERS - 1) ? 1 : 0);
        cur = out;
    }
}

// Round 6
// 1534.364 us; speedup vs baseline: 1.2293x; 1.2293x over previous
//
#include <hip/hip_runtime.h>
#include <hip/hip_fp16.h>

#define N_NODES 100000
#define N_EDGES 1600000
#define C_DIM 128
#define EC_DIM 16
#define L_LAYERS 3
#define G_GRAPHS 256
#define GN_EPS 1e-5f
#define SCAN_BLOCKS 391   // ceil(100000/256)

typedef __attribute__((ext_vector_type(8))) _Float16 f16x8;
typedef __attribute__((ext_vector_type(4))) float f32x4;

__device__ __forceinline__ float silu_f(float v) {
    return v / (1.0f + __expf(-v));
}

__device__ __forceinline__ float4 ld4(const float* p) { return *(const float4*)p; }
__device__ __forceinline__ void st4(float* p, float4 v) { *(float4*)p = v; }
__device__ __forceinline__ float4 fma4(float s, float4 w, float4 a) {
    a.x = fmaf(s, w.x, a.x); a.y = fmaf(s, w.y, a.y);
    a.z = fmaf(s, w.z, a.z); a.w = fmaf(s, w.w, a.w);
    return a;
}

// ---------------- graph bookkeeping (GraphNorm segments) ----------------

__global__ void zero_cnt_kernel(int* cnt) { cnt[threadIdx.x] = 0; }

__global__ void count_kernel(const int* __restrict__ batch, int* __restrict__ cnt) {
    int i = blockIdx.x * blockDim.x + threadIdx.x;
    if (i < N_NODES) atomicAdd(&cnt[batch[i]], 1);
}

__global__ void scan_kernel(const int* __restrict__ cnt, int* __restrict__ start,
                            float* __restrict__ cntf) {
    __shared__ int s[G_GRAPHS];
    int t = threadIdx.x;
    int v = cnt[t];
    s[t] = v;
    __syncthreads();
    for (int off = 1; off < G_GRAPHS; off <<= 1) {
        int add = (t >= off) ? s[t - off] : 0;
        __syncthreads();
        s[t] += add;
        __syncthreads();
    }
    start[t] = s[t] - v;
    cntf[t] = (float)v;
}

// ---------------- CSR build (by dst) ----------------

__global__ void deg_count_kernel(const int* __restrict__ eidx, int* __restrict__ deg) {
    int e = blockIdx.x * blockDim.x + threadIdx.x;
    if (e < N_EDGES) atomicAdd(&deg[eidx[N_EDGES + e]], 1);
}

__global__ void scanA_kernel(const int* __restrict__ deg, int* __restrict__ rpl,
                             int* __restrict__ bsum) {
    __shared__ int s[256];
    int i = blockIdx.x * 256 + threadIdx.x;
    int v = (i < N_NODES) ? deg[i] : 0;
    s[threadIdx.x] = v;
    __syncthreads();
    for (int off = 1; off < 256; off <<= 1) {
        int add = (threadIdx.x >= off) ? s[threadIdx.x - off] : 0;
        __syncthreads();
        s[threadIdx.x] += add;
        __syncthreads();
    }
    if (i < N_NODES) rpl[i] = s[threadIdx.x] - v;
    if (threadIdx.x == 255) bsum[blockIdx.x] = s[255];
}

__global__ void scanB_kernel(const int* __restrict__ bsum, int* __restrict__ boff) {
    __shared__ int s[512];
    int t = threadIdx.x;
    int v = (t < SCAN_BLOCKS) ? bsum[t] : 0;
    s[t] = v;
    __syncthreads();
    for (int off = 1; off < 512; off <<= 1) {
        int add = (t >= off) ? s[t - off] : 0;
        __syncthreads();
        s[t] += add;
        __syncthreads();
    }
    if (t < SCAN_BLOCKS) boff[t] = s[t] - v;
}

__global__ void scanC_kernel(const int* __restrict__ rpl, const int* __restrict__ boff,
                             int* __restrict__ rp, int* __restrict__ cursor) {
    int i = blockIdx.x * 256 + threadIdx.x;
    if (i < N_NODES) {
        int v = rpl[i] + boff[blockIdx.x];
        rp[i] = v;
        cursor[i] = v;
    }
    if (i == 0) rp[N_NODES] = N_EDGES;
}

__global__ void fill_kernel(const int* __restrict__ eidx, int* __restrict__ cursor,
                            int* __restrict__ srcs, int* __restrict__ eid) {
    int e = blockIdx.x * blockDim.x + threadIdx.x;
    if (e >= N_EDGES) return;
    int src = eidx[e];
    int dst = eidx[N_EDGES + e];
    int pos = atomicAdd(&cursor[dst], 1);
    srcs[pos] = src;
    eid[pos] = e;
}

// ---------------- one-time reorder: eac[pos] = edge_attr[eid[pos]] --------
__global__ __launch_bounds__(256) void eacopy_kernel(
    const float* __restrict__ ea, const int* __restrict__ eid,
    float4* __restrict__ eac)
{
    long long t = (long long)blockIdx.x * blockDim.x + threadIdx.x;
    int pos = (int)(t >> 2), q = (int)(t & 3);
    if (pos >= N_EDGES) return;
    int e = eid[pos];
    eac[(size_t)pos * 4 + q] = ((const float4*)(ea + (size_t)e * EC_DIM))[q];
}

// ---------------- one-time cast: xh = fp16(x) ----------------
__global__ __launch_bounds__(256) void xcast_kernel(
    const float* __restrict__ x, __half2* __restrict__ xh)
{
    int i = blockIdx.x * blockDim.x + threadIdx.x;   // N*C/2 elements
    if (i < N_NODES * C_DIM / 2) {
        float2 v = ((const float2*)x)[i];
        xh[i] = __floats2half2_rn(v.x, v.y);
    }
}

// ---------------- one-time: Wt[l][c][k] = fp16(W[l][k][c]) ----------------
__global__ __launch_bounds__(256) void wtcast_kernel(
    const float* __restrict__ W, __half* __restrict__ Wt)
{
    int l = blockIdx.y;
    int t = blockIdx.x * 256 + threadIdx.x;     // 0..16383
    int c = t >> 7, k = t & 127;
    Wt[(size_t)l * 16384 + (size_t)c * 128 + k] =
        __float2half_rn(W[(size_t)l * 16384 + (size_t)k * 128 + c]);
}

// ---------------- fused gather ----------------
// One wave per node; wave walks the node's CSR range, one edge/iter.
// n readfirstlane'd -> srcs[j]/ea row provably uniform -> SGPR loads.
// __launch_bounds__(256, 2): min 2 waves/EU -> 256-VGPR budget, so the
// allocator has no occupancy incentive to rematerialize the 16 float2 W
// loads inside the loop (round-3/4 evidence: default target squeezed to
// 24-28 VGPRs and reloaded W every edge; KEEPW asm made it worse).
// BIG: writes fp16 (consumed by fp16 MFMA GEMM1).

#define DECLW(k) const float2 w##k = *(const float2*)(Wp + (k) * C_DIM);

#define EDGE_PROJ(QA, QB, QC, QD, ZX, ZY) \
    ZX = b2.x; ZY = b2.y; \
    ZX = fmaf(QA.x, w0.x,  ZX); ZY = fmaf(QA.x, w0.y,  ZY); \
    ZX = fmaf(QA.y, w1.x,  ZX); ZY = fmaf(QA.y, w1.y,  ZY); \
    ZX = fmaf(QA.z, w2.x,  ZX); ZY = fmaf(QA.z, w2.y,  ZY); \
    ZX = fmaf(QA.w, w3.x,  ZX); ZY = fmaf(QA.w, w3.y,  ZY); \
    ZX = fmaf(QB.x, w4.x,  ZX); ZY = fmaf(QB.x, w4.y,  ZY); \
    ZX = fmaf(QB.y, w5.x,  ZX); ZY = fmaf(QB.y, w5.y,  ZY); \
    ZX = fmaf(QB.z, w6.x,  ZX); ZY = fmaf(QB.z, w6.y,  ZY); \
    ZX = fmaf(QB.w, w7.x,  ZX); ZY = fmaf(QB.w, w7.y,  ZY); \
    ZX = fmaf(QC.x, w8.x,  ZX); ZY = fmaf(QC.x, w8.y,  ZY); \
    ZX = fmaf(QC.y, w9.x,  ZX); ZY = fmaf(QC.y, w9.y,  ZY); \
    ZX = fmaf(QC.z, w10.x, ZX); ZY = fmaf(QC.z, w10.y, ZY); \
    ZX = fmaf(QC.w, w11.x, ZX); ZY = fmaf(QC.w, w11.y, ZY); \
    ZX = fmaf(QD.x, w12.x, ZX); ZY = fmaf(QD.x, w12.y, ZY); \
    ZX = fmaf(QD.y, w13.x, ZX); ZY = fmaf(QD.y, w13.y, ZY); \
    ZX = fmaf(QD.z, w14.x, ZX); ZY = fmaf(QD.z, w14.y, ZY); \
    ZX = fmaf(QD.w, w15.x, ZX); ZY = fmaf(QD.w, w15.y, ZY);

template<bool BIG>
__global__ __launch_bounds__(256, 2) void gatherf_kernel(
    const float* __restrict__ x, const __half* __restrict__ xh,
    const float* __restrict__ ea, const float* __restrict__ eac,
    const int* __restrict__ srcs, const int* __restrict__ eid,
    const int* __restrict__ rp,
    const float* __restrict__ W, const float* __restrict__ bias,
    float* __restrict__ hb, __half* __restrict__ hb16)
{
    int n = (blockIdx.x * blockDim.x + threadIdx.x) >> 6;
    n = __builtin_amdgcn_readfirstlane(n);   // provably wave-uniform
    if (n >= N_NODES) return;
    const int lane = threadIdx.x & 63;
    const int c2 = lane * 2;
    const float* Wp = W + c2;
    DECLW(0)  DECLW(1)  DECLW(2)  DECLW(3)
    DECLW(4)  DECLW(5)  DECLW(6)  DECLW(7)
    DECLW(8)  DECLW(9)  DECLW(10) DECLW(11)
    DECLW(12) DECLW(13) DECLW(14) DECLW(15)
    const float2 b2 = *(const float2*)(bias + c2);

    float accx = 0.f, accy = 0.f;
    const int beg = rp[n], end = rp[n + 1];
    for (int j = beg; j < end; ++j) {
        const int src = srcs[j];            // uniform -> s_load
        float4 A0, A1, A2, A3;
        float xsx, xsy;
        if (BIG) {
            const float* ep = eac + (size_t)j * EC_DIM;   // uniform row
            A0 = ld4(ep);     A1 = ld4(ep + 4);
            A2 = ld4(ep + 8); A3 = ld4(ep + 12);
            const __half2 xv = *(const __half2*)(xh + (size_t)src * C_DIM + c2);
            const float2 xf = __half22float2(xv);
            xsx = xf.x; xsy = xf.y;
        } else {
            const int e = eid[j];                          // uniform
            const float* ep = ea + (size_t)e * EC_DIM;     // uniform row
            A0 = ld4(ep);     A1 = ld4(ep + 4);
            A2 = ld4(ep + 8); A3 = ld4(ep + 12);
            const float2 xf = *(const float2*)(x + (size_t)src * C_DIM + c2);
            xsx = xf.x; xsy = xf.y;
        }
        float zx, zy;
        EDGE_PROJ(A0, A1, A2, A3, zx, zy)
        accx += fmaxf(xsx + silu_f(zx), 0.f);
        accy += fmaxf(xsy + silu_f(zy), 0.f);
    }
    const float2 xo = *(const float2*)(x + (size_t)n * C_DIM + c2);
    if (BIG) {
        *(__half2*)(hb16 + (size_t)n * C_DIM + c2) =
            __floats2half2_rn(xo.x + accx, xo.y + accy);
    } else {
        *(float2*)(hb + (size_t)n * C_DIM + c2) = make_float2(xo.x + accx, xo.y + accy);
    }
}

// ---------------- MFMA fp16 GEMM: out[N,128] = act(A@W + b) ----------------
// A fp16 row-major [N,128]; Wt fp16 [c][k] (W pre-transposed). 4 waves/block,
// each wave computes 16 rows x 128 cols via 8 n-tiles x 4 k-tiles of
// mfma_f32_16x16x32_f16. A/B frags both loaded with the SAME (lane,i)->k
// formula, so any k-permutation mismatch with HW cancels in the contraction.
// C/D mapping (HW-verified): col = lane&15, row = (lane>>4)*4 + reg.
template<bool SILU, bool OUT16>
__global__ __launch_bounds__(256) void gemm_mfma_kernel(
    const __half* __restrict__ A16, const __half* __restrict__ Wt,
    const float* __restrict__ bias, float* __restrict__ outf,
    __half* __restrict__ out16)
{
    const int wid  = threadIdx.x >> 6;       // 0..3
    const int lane = threadIdx.x & 63;
    const int r16  = lane & 15;
    const int kq   = lane >> 4;              // 0..3
    const int rowbase = blockIdx.x * 64 + wid * 16;

    f32x4 acc[8];
#pragma unroll
    for (int nt = 0; nt < 8; ++nt) {
        float bv = bias[nt * 16 + r16];
        acc[nt] = (f32x4){bv, bv, bv, bv};
    }

    int arow = rowbase + r16;
    if (arow >= N_NODES) arow = N_NODES - 1;           // tail clamp (loads only)
    const __half* Ar = A16 + (size_t)arow * C_DIM + kq * 8;
    const __half* Br = Wt + (size_t)r16 * C_DIM + kq * 8;

#pragma unroll
    for (int kt = 0; kt < 4; ++kt) {
        const f16x8 af = *(const f16x8*)(Ar + kt * 32);
#pragma unroll
        for (int nt = 0; nt < 8; ++nt) {
            const f16x8 bf = *(const f16x8*)(Br + (size_t)nt * 16 * C_DIM + kt * 32);
            acc[nt] = __builtin_amdgcn_mfma_f32_16x16x32_f16(af, bf, acc[nt], 0, 0, 0);
        }
    }

#pragma unroll
    for (int nt = 0; nt < 8; ++nt) {
#pragma unroll
        for (int j = 0; j < 4; ++j) {
            float v = acc[nt][j];
            if (SILU) v = silu_f(v);
            const int m = rowbase + kq * 4 + j;
            const int nc = nt * 16 + r16;
            if (m < N_NODES) {
                if (OUT16) out16[(size_t)m * C_DIM + nc] = __float2half_rn(v);
                else       outf[(size_t)m * C_DIM + nc] = v;
            }
        }
    }
}

// ---------------- fp32 GEMM (fallback path) ----------------
template<bool SILU>
__global__ __launch_bounds__(256) void gemm128_kernel(
    const float* __restrict__ A, const float* __restrict__ W,
    const float* __restrict__ bias, float* __restrict__ out)
{
    __shared__ float Wl[C_DIM * C_DIM];   // 64 KB
    const int tid = threadIdx.x;
    const int rowbase = blockIdx.x * 32;
#pragma unroll
    for (int i = 0; i < 16; ++i)
        ((float4*)Wl)[i * 256 + tid] = ((const float4*)W)[i * 256 + tid];
    __syncthreads();

    const int cx = tid & 31;
    const int ry = tid >> 5;
    const float4 bias4 = ld4(bias + cx * 4);
    float4 acc[4] = {bias4, bias4, bias4, bias4};
    const float* Ab = A + (size_t)(rowbase + ry * 4) * C_DIM;

    for (int k = 0; k < C_DIM; k += 4) {
        float4 a[4], w[4];
#pragma unroll
        for (int rr = 0; rr < 4; ++rr) a[rr] = ld4(Ab + rr * C_DIM + k);
#pragma unroll
        for (int kk = 0; kk < 4; ++kk) w[kk] = *(const float4*)&Wl[(k + kk) * C_DIM + cx * 4];
#pragma unroll
        for (int rr = 0; rr < 4; ++rr) {
            acc[rr] = fma4(a[rr].x, w[0], acc[rr]);
            acc[rr] = fma4(a[rr].y, w[1], acc[rr]);
            acc[rr] = fma4(a[rr].z, w[2], acc[rr]);
            acc[rr] = fma4(a[rr].w, w[3], acc[rr]);
        }
    }
#pragma unroll
    for (int rr = 0; rr < 4; ++rr) {
        float4 v = acc[rr];
        if (SILU) { v.x = silu_f(v.x); v.y = silu_f(v.y); v.z = silu_f(v.z); v.w = silu_f(v.w); }
        st4(out + (size_t)(rowbase + ry * 4 + rr) * C_DIM + cx * 4, v);
    }
}

// ---------------- GraphNorm ----------------
__global__ __launch_bounds__(1024) void gn_reduce_kernel(
    const float* __restrict__ h, const int* __restrict__ start,
    const int* __restrict__ cnt, const float* __restrict__ cntf,
    const float* __restrict__ ms, float* __restrict__ meansc,
    float* __restrict__ rstd)
{
    const int g = blockIdx.x;
    const int c = threadIdx.x & 127;
    const int sub = threadIdx.x >> 7;       // 0..7
    const int s0 = start[g];
    const int n = cnt[g];
    float sum = 0.f, sq = 0.f;
    for (int r = sub; r < n; r += 8) {
        float v = h[(size_t)(s0 + r) * C_DIM + c];
        sum += v; sq += v * v;
    }
    __shared__ float ls[1024], lq[1024];
    ls[threadIdx.x] = sum; lq[threadIdx.x] = sq;
    __syncthreads();
    if (threadIdx.x < 512) {
        ls[threadIdx.x] += ls[threadIdx.x + 512];
        lq[threadIdx.x] += lq[threadIdx.x + 512];
    }
    __syncthreads();
    if (threadIdx.x < 256) {
        ls[threadIdx.x] += ls[threadIdx.x + 256];
        lq[threadIdx.x] += lq[threadIdx.x + 256];
    }
    __syncthreads();
    if (threadIdx.x < 128) {
        sum = ls[threadIdx.x] + ls[threadIdx.x + 128];
        sq  = lq[threadIdx.x] + lq[threadIdx.x + 128];
        const float cn = cntf[g];
        const float mean = sum / cn;
        const float msq = sq / cn;
        const float s = ms[c];
        const float var = msq - (2.0f * s - s * s) * mean * mean;
        meansc[(size_t)g * C_DIM + c] = mean * s;
        rstd[(size_t)g * C_DIM + c] = 1.0f / sqrtf(var + GN_EPS);
    }
}

__global__ __launch_bounds__(256) void gn_norm_kernel(
    const float* __restrict__ h, const int* __restrict__ batch,
    const float* __restrict__ meansc, const float* __restrict__ rstd,
    const float* __restrict__ gw, const float* __restrict__ gb,
    float* __restrict__ out, __half* __restrict__ xh, int wxh)
{
    const int id = blockIdx.x * blockDim.x + threadIdx.x;
    const int row = id >> 5;
    const int c4 = (id & 31) * 4;
    if (row >= N_NODES) return;
    const int g = batch[row];
    const float4 hv = ld4(h + (size_t)row * C_DIM + c4);
    const float4 m = ld4(meansc + (size_t)g * C_DIM + c4);
    const float4 r = ld4(rstd + (size_t)g * C_DIM + c4);
    const float4 w = ld4(gw + c4);
    const float4 b = ld4(gb + c4);
    float4 o;
    o.x = fmaf((hv.x - m.x) * r.x, w.x, b.x);
    o.y = fmaf((hv.y - m.y) * r.y, w.y, b.y);
    o.z = fmaf((hv.z - m.z) * r.z, w.z, b.z);
    o.w = fmaf((hv.w - m.w) * r.w, w.w, b.w);
    st4(out + (size_t)row * C_DIM + c4, o);
    if (wxh) {
        __half2* xp = (__half2*)(xh + (size_t)row * C_DIM + c4);
        xp[0] = __floats2half2_rn(o.x, o.y);
        xp[1] = __floats2half2_rn(o.z, o.w);
    }
}

// ---------------- launch ----------------

extern "C" void kernel_launch(void* const* d_in, const int* in_sizes, int n_in,
                              void* d_out, int out_size, void* d_ws, size_t ws_size,
                              hipStream_t stream)
{
    const float* x_in      = (const float*)d_in[0];
    const float* edge_attr = (const float*)d_in[1];
    const int*   edge_idx  = (const int*)d_in[2];
    const int*   batch     = (const int*)d_in[3];
    const float* lew       = (const float*)d_in[4];
    const float* leb       = (const float*)d_in[5];
    const float* w1        = (const float*)d_in[6];
    const float* b1        = (const float*)d_in[7];
    const float* w2        = (const float*)d_in[8];
    const float* b2        = (const float*)d_in[9];
    const float* gnw       = (const float*)d_in[10];
    const float* gnb       = (const float*)d_in[11];
    const float* gms       = (const float*)d_in[12];
    float* out = (float*)d_out;

    // workspace layout — every region padded to 256 B so all float4/f16x8
    // vector accesses are naturally aligned (round-5 hazard: hb16/t16 landed
    // at 8-mod-16 byte offsets under element-count packing).
    char* base = (char*)d_ws;
    size_t off = 0;
    auto alloc = [&](size_t bytes) -> void* {
        void* p = base + off;
        off = (off + bytes + 255) & ~(size_t)255;
        return p;
    };
    float* hbuf   = (float*)alloc((size_t)N_NODES * C_DIM * 4);
    float* meansc = (float*)alloc((size_t)G_GRAPHS * C_DIM * 4);
    float* rstd   = (float*)alloc((size_t)G_GRAPHS * C_DIM * 4);
    float* cntf   = (float*)alloc(G_GRAPHS * 4);
    int*   cnti   = (int*)alloc(G_GRAPHS * 4);
    int*   startg = (int*)alloc(G_GRAPHS * 4);
    int*   deg    = (int*)alloc((size_t)N_NODES * 4);
    int*   rpl    = (int*)alloc((size_t)N_NODES * 4);
    int*   bsum   = (int*)alloc(512 * 4);
    int*   boff   = (int*)alloc(512 * 4);
    int*   rp     = (int*)alloc(((size_t)N_NODES + 2) * 4);
    int*   cursor = (int*)alloc((size_t)N_NODES * 4);
    int*   srcs   = (int*)alloc((size_t)N_EDGES * 4);
    int*   eid    = (int*)alloc((size_t)N_EDGES * 4);
    float* eac    = (float*)alloc((size_t)N_EDGES * EC_DIM * 4);   // big only
    __half* xh    = (__half*)alloc((size_t)N_NODES * C_DIM * 2);   // big only
    __half* hb16  = (__half*)alloc((size_t)N_NODES * C_DIM * 2);   // big only
    __half* t16   = (__half*)alloc((size_t)N_NODES * C_DIM * 2);   // big only
    __half* wt6   = (__half*)alloc((size_t)6 * 16384 * 2);         // big only

    const size_t need_big = off;
    const bool big = ws_size >= need_big;

    // GraphNorm segment bookkeeping
    zero_cnt_kernel<<<1, G_GRAPHS, 0, stream>>>(cnti);
    count_kernel<<<(N_NODES + 255) / 256, 256, 0, stream>>>(batch, cnti);
    scan_kernel<<<1, G_GRAPHS, 0, stream>>>(cnti, startg, cntf);

    // CSR build (by dst), once per call
    hipMemsetAsync(deg, 0, (size_t)N_NODES * sizeof(int), stream);
    deg_count_kernel<<<(N_EDGES + 255) / 256, 256, 0, stream>>>(edge_idx, deg);
    scanA_kernel<<<SCAN_BLOCKS, 256, 0, stream>>>(deg, rpl, bsum);
    scanB_kernel<<<1, 512, 0, stream>>>(bsum, boff);
    scanC_kernel<<<SCAN_BLOCKS, 256, 0, stream>>>(rpl, boff, rp, cursor);
    fill_kernel<<<(N_EDGES + 255) / 256, 256, 0, stream>>>(edge_idx, cursor, srcs, eid);

    if (big) {
        eacopy_kernel<<<(int)(((size_t)N_EDGES * 4 + 255) / 256), 256, 0, stream>>>(
            edge_attr, eid, (float4*)eac);
        xcast_kernel<<<(int)(((size_t)N_NODES * C_DIM / 2 + 255) / 256), 256, 0, stream>>>(
            x_in, (__half2*)xh);
        wtcast_kernel<<<dim3(64, 3), 256, 0, stream>>>(w1, wt6);
        wtcast_kernel<<<dim3(64, 3), 256, 0, stream>>>(w2, wt6 + 3 * 16384);
    }

    const float* cur = x_in;
    for (int l = 0; l < L_LAYERS; ++l) {
        if (big) {
            gatherf_kernel<true><<<(int)(((size_t)N_NODES * 64 + 255) / 256), 256, 0, stream>>>(
                cur, xh, edge_attr, eac, srcs, eid, rp, lew, leb, hbuf, hb16);
            gemm_mfma_kernel<true, true><<<(N_NODES + 63) / 64, 256, 0, stream>>>(
                hb16, wt6 + (size_t)l * 16384, b1 + (size_t)l * C_DIM, hbuf, t16);
            gemm_mfma_kernel<false, false><<<(N_NODES + 63) / 64, 256, 0, stream>>>(
                t16, wt6 + (size_t)(3 + l) * 16384, b2 + (size_t)l * C_DIM, hbuf, t16);
        } else {
            gatherf_kernel<false><<<(int)(((size_t)N_NODES * 64 + 255) / 256), 256, 0, stream>>>(
                cur, xh, edge_attr, eac, srcs, eid, rp, lew, leb, hbuf, hb16);
            gemm128_kernel<true><<<N_NODES / 32, 256, 0, stream>>>(
                hbuf, w1 + (size_t)l * C_DIM * C_DIM, b1 + (size_t)l * C_DIM, out);
            gemm128_kernel<false><<<N_NODES / 32, 256, 0, stream>>>(
                out, w2 + (size_t)l * C_DIM * C_DIM, b2 + (size_t)l * C_DIM, hbuf);
        }
        gn_reduce_kernel<<<G_GRAPHS, 1024, 0, stream>>>(
            hbuf, startg, cnti, cntf, gms + (size_t)l * C_DIM, meansc, rstd);
        gn_norm_kernel<<<(int)(((size_t)N_NODES * 32 + 255) / 256), 256, 0, stream>>>(
            hbuf, batch, meansc, rstd, gnw + (size_t)l * C_DIM, gnb + (size_t)l * C_DIM,
            out, xh, (big && l < L_LAYERS - 1) ? 1 : 0);
        cur = out;
    }
}